// Round 7
// baseline (597.510 us; speedup 1.0000x reference)
//
#include <hip/hip_runtime.h>
#include <hip/hip_bf16.h>

// GCN 2-layer encoder: N=100000 nodes, E=3.2M edges, Fin=256, Fh=128, Fo=64.
//   h1 = x@W1 ; a1 = relu(A@h1 + b1) ; h2 = a1@W2 ; out = A@h2 + b2
// A includes self-loops (w=1), symmetric rsqrt-degree normalization.
//
// R7: (a) hist+gemm1 fusion now STRIPE-interleaved (bid%9==8 -> gemm) so
// both roles are co-resident all kernel long (R6's block-ordered fusion
// only overlapped at the boundary). (b) a1 stored fp16 (feeds gemm2 only;
// ~1e-4 at output). (c) nontemporal edge-stream loads in agg1/agg2 to
// preserve L2 for the h-row gathers. CSR via packed-u64 atomic
// (count<<42 | fixed-point wdeg; returned old>>42 = stable position).

#define FIN 256
#define FH  128
#define FO  64

#define CNT_SHIFT 42
#define WSCALE 1073741824.0f          // 2^30
#define WINV   (1.0f / 1073741824.0f)
#define LOWMASK ((1ULL << CNT_SHIFT) - 1ULL)
#define RATIO 8                        // hist blocks per gemm block

__device__ __forceinline__ float h2f(unsigned int u16) {
  union { unsigned short s; _Float16 h; } c; c.s = (unsigned short)u16;
  return (float)c.h;
}
__device__ __forceinline__ unsigned int f2h(float f) {
  union { _Float16 h; unsigned short s; } c; c.h = (_Float16)f;  // RNE cvt
  return (unsigned int)c.s;
}

// ---------------- fused: stripe-interleaved hist (8/9) + gemm1 (1/9)
__global__ __launch_bounds__(256) void hist_gemm1_kernel(
    const int* __restrict__ dst, const float* __restrict__ w,
    unsigned long long* __restrict__ cnt64, int* __restrict__ pos, int E,
    const float* __restrict__ X, const float* __restrict__ W,
    unsigned short* __restrict__ H1h, int N, int NBG) {
  __shared__ __align__(16) float xs[64][17];
  __shared__ __align__(16) float wsm[16 * FH];
  int bid = blockIdx.x;
  int tid = threadIdx.x;
  int g = bid / (RATIO + 1);
  int r = bid - g * (RATIO + 1);
  if (r != RATIO) {
    // ---- histogram role: one u64 atomic per edge; returns stable position
    int e = (g * RATIO + r) * 256 + tid;
    if (e < E) {
      int d = dst[e];
      unsigned long long v = (1ULL << CNT_SHIFT)
                           + (unsigned long long)(w[e] * WSCALE);
      unsigned long long old = atomicAdd(&cnt64[d], v);
      pos[e] = (int)(old >> CNT_SHIFT);
    }
    return;
  }
  if (g >= NBG) return;
  // ---- gemm1 role: H1h[64 rows, 128 cols] fp16 = X @ W1
  int row0 = g * 64;
  int tx = tid & 31;        // cols tx*4 .. +3
  int ty = tid >> 5;        // rows ty*8 .. +7
  float acc[8][4];
  #pragma unroll
  for (int i = 0; i < 8; ++i)
    #pragma unroll
    for (int j = 0; j < 4; ++j) acc[i][j] = 0.f;

  for (int k0 = 0; k0 < FIN; k0 += 16) {
    {
      int rr = tid >> 2, kq = (tid & 3) * 4;
      int gr = row0 + rr;
      float4 v = make_float4(0.f, 0.f, 0.f, 0.f);
      if (gr < N) v = *(const float4*)(X + (size_t)gr * FIN + k0 + kq);
      xs[rr][kq + 0] = v.x; xs[rr][kq + 1] = v.y;
      xs[rr][kq + 2] = v.z; xs[rr][kq + 3] = v.w;
    }
    {
      const float4* s4 = (const float4*)(W + (size_t)k0 * FH);
      float4* d4 = (float4*)wsm;
      d4[tid] = s4[tid];
      d4[tid + 256] = s4[tid + 256];
    }
    __syncthreads();
    #pragma unroll
    for (int kk = 0; kk < 16; ++kk) {
      float xv[8];
      #pragma unroll
      for (int i = 0; i < 8; ++i) xv[i] = xs[ty * 8 + i][kk];
      float4 wv = *(const float4*)(&wsm[kk * FH + tx * 4]);
      #pragma unroll
      for (int i = 0; i < 8; ++i) {
        acc[i][0] += xv[i] * wv.x; acc[i][1] += xv[i] * wv.y;
        acc[i][2] += xv[i] * wv.z; acc[i][3] += xv[i] * wv.w;
      }
    }
    __syncthreads();
  }
  #pragma unroll
  for (int i = 0; i < 8; ++i) {
    int gr = row0 + ty * 8 + i;
    if (gr < N) {
      uint2 pk;
      pk.x = f2h(acc[i][0]) | (f2h(acc[i][1]) << 16);
      pk.y = f2h(acc[i][2]) | (f2h(acc[i][3]) << 16);
      *(uint2*)(H1h + (size_t)gr * FH + tx * 4) = pk;
    }
  }
}

// ---------------- 3-phase exclusive scan of cnt64>>42 -> rowptr; also dinv
__global__ __launch_bounds__(256) void scan1_kernel(
    const unsigned long long* __restrict__ cnt64, int* __restrict__ rowptr,
    int* __restrict__ bsum, float* __restrict__ dinv, int N) {
  __shared__ int tot[256];
  int t = threadIdx.x;
  int base = blockIdx.x * 1024 + t * 4;
  int v0 = 0, v1 = 0, v2 = 0, v3 = 0;
  #pragma unroll
  for (int q = 0; q < 4; ++q) {
    int idx = base + q;
    if (idx < N) {
      unsigned long long c = cnt64[idx];
      int cv = (int)(c >> CNT_SHIFT);
      float deg = (float)(c & LOWMASK) * WINV;
      dinv[idx] = rsqrtf(1.0f + deg);
      if (q == 0) v0 = cv; else if (q == 1) v1 = cv;
      else if (q == 2) v2 = cv; else v3 = cv;
    }
  }
  int s = v0 + v1 + v2 + v3;
  tot[t] = s;
  __syncthreads();
  for (int off = 1; off < 256; off <<= 1) {
    int y = (t >= off) ? tot[t - off] : 0;
    __syncthreads();
    tot[t] += y;
    __syncthreads();
  }
  int p = tot[t] - s;  // exclusive within block
  if (t == 255) bsum[blockIdx.x] = tot[255];
  if (base + 0 < N) rowptr[base + 0] = p; p += v0;
  if (base + 1 < N) rowptr[base + 1] = p; p += v1;
  if (base + 2 < N) rowptr[base + 2] = p; p += v2;
  if (base + 3 < N) rowptr[base + 3] = p;
}

__global__ __launch_bounds__(256) void scan2_kernel(
    int* __restrict__ bsum, int* __restrict__ rowptrN, int nb, int E) {
  __shared__ int buf[256];
  int t = threadIdx.x;
  int v = (t < nb) ? bsum[t] : 0;
  buf[t] = v;
  __syncthreads();
  for (int off = 1; off < 256; off <<= 1) {
    int y = (t >= off) ? buf[t - off] : 0;
    __syncthreads();
    buf[t] += y;
    __syncthreads();
  }
  if (t < nb) bsum[t] = buf[t] - v;  // exclusive
  if (t == 0) rowptrN[0] = E;
}

__global__ __launch_bounds__(256) void scan3_kernel(
    int* __restrict__ rowptr, const int* __restrict__ bsum, int N) {
  int i = blockIdx.x * 256 + threadIdx.x;
  if (i < N) rowptr[i] += bsum[i >> 10];
}

// ---------------- scatter (atomic-free): edges[rowptr[d]+pos[e]] = {src, norm}
__global__ __launch_bounds__(256) void scatter_kernel(
    const int* __restrict__ src, const int* __restrict__ dst,
    const float* __restrict__ w, const int* __restrict__ rowptr,
    const int* __restrict__ pos, const float* __restrict__ dinv,
    int2* __restrict__ edges, int E) {
  int e = blockIdx.x * 256 + threadIdx.x;
  if (e < E) {
    int s = src[e], d = dst[e];
    float nm = dinv[s] * w[e] * dinv[d];
    edges[rowptr[d] + pos[e]] = make_int2(s, __float_as_int(nm));
  }
}

// ---------------- GEMM2: H2h[N,64](fp16) = A1h[N,128](fp16) @ W2[128,64]
__global__ __launch_bounds__(256) void gemm2_kernel(
    const unsigned short* __restrict__ A1h, const float* __restrict__ W2,
    unsigned short* __restrict__ H2h, int N) {
  __shared__ __align__(16) float xs[64][17];
  __shared__ __align__(16) float ws[16 * FO];
  int tid = threadIdx.x;
  int row0 = blockIdx.x * 64;
  int tx = tid & 15;        // cols tx*4..+3
  int ty = tid >> 4;        // rows ty*4..+3
  float acc[4][4];
  #pragma unroll
  for (int i = 0; i < 4; ++i)
    #pragma unroll
    for (int j = 0; j < 4; ++j) acc[i][j] = 0.f;

  for (int k0 = 0; k0 < FH; k0 += 16) {
    {
      int r = tid >> 2, kq = (tid & 3) * 4;
      int gr = row0 + r;
      uint2 v = make_uint2(0u, 0u);
      if (gr < N) v = *(const uint2*)(A1h + (size_t)gr * FH + k0 + kq);
      xs[r][kq + 0] = h2f(v.x & 0xffffu); xs[r][kq + 1] = h2f(v.x >> 16);
      xs[r][kq + 2] = h2f(v.y & 0xffffu); xs[r][kq + 3] = h2f(v.y >> 16);
    }
    {
      const float4* s4 = (const float4*)(W2 + (size_t)k0 * FO);
      float4* d4 = (float4*)ws;
      d4[tid] = s4[tid];
    }
    __syncthreads();
    #pragma unroll
    for (int kk = 0; kk < 16; ++kk) {
      float xv[4];
      #pragma unroll
      for (int i = 0; i < 4; ++i) xv[i] = xs[ty * 4 + i][kk];
      float4 wv = *(const float4*)(&ws[kk * FO + tx * 4]);
      #pragma unroll
      for (int i = 0; i < 4; ++i) {
        acc[i][0] += xv[i] * wv.x; acc[i][1] += xv[i] * wv.y;
        acc[i][2] += xv[i] * wv.z; acc[i][3] += xv[i] * wv.w;
      }
    }
    __syncthreads();
  }
  #pragma unroll
  for (int i = 0; i < 4; ++i) {
    int gr = row0 + ty * 4 + i;
    if (gr < N) {
      uint2 pk;
      pk.x = f2h(acc[i][0]) | (f2h(acc[i][1]) << 16);
      pk.y = f2h(acc[i][2]) | (f2h(acc[i][3]) << 16);
      *(uint2*)(H2h + (size_t)gr * FO + tx * 4) = pk;
    }
  }
}

// ---------------- aggregation layer 1: a1h = relu(A @ h1 + b1), fp16 out
// one wave per node, wave-uniform edge loop, x4 unroll, nontemporal edges
__global__ __launch_bounds__(256) void agg1_kernel(
    const unsigned short* __restrict__ H1h, const int2* __restrict__ edges,
    const int* __restrict__ rowptr, const float* __restrict__ dinv,
    const float* __restrict__ b1, unsigned short* __restrict__ A1h, int N) {
  int wid = (blockIdx.x * 256 + threadIdx.x) >> 6;
  int lane = threadIdx.x & 63;
  if (wid >= N) return;
  int p0 = rowptr[wid], p1 = rowptr[wid + 1];
  float ax0 = 0.f, ay0 = 0.f, ax1 = 0.f, ay1 = 0.f;
  float ax2 = 0.f, ay2 = 0.f, ax3 = 0.f, ay3 = 0.f;
  const unsigned long long* ep = (const unsigned long long*)edges;
  int p = p0;
  for (; p + 4 <= p1; p += 4) {
    unsigned long long e0 = __builtin_nontemporal_load(ep + p);
    unsigned long long e1 = __builtin_nontemporal_load(ep + p + 1);
    unsigned long long e2 = __builtin_nontemporal_load(ep + p + 2);
    unsigned long long e3 = __builtin_nontemporal_load(ep + p + 3);
    unsigned int h0 = *(const unsigned int*)(H1h + (size_t)(unsigned int)(e0 & 0xffffffffu) * FH + lane * 2);
    unsigned int h1 = *(const unsigned int*)(H1h + (size_t)(unsigned int)(e1 & 0xffffffffu) * FH + lane * 2);
    unsigned int h2 = *(const unsigned int*)(H1h + (size_t)(unsigned int)(e2 & 0xffffffffu) * FH + lane * 2);
    unsigned int h3 = *(const unsigned int*)(H1h + (size_t)(unsigned int)(e3 & 0xffffffffu) * FH + lane * 2);
    float n0 = __uint_as_float((unsigned int)(e0 >> 32));
    float n1 = __uint_as_float((unsigned int)(e1 >> 32));
    float n2 = __uint_as_float((unsigned int)(e2 >> 32));
    float n3 = __uint_as_float((unsigned int)(e3 >> 32));
    ax0 += n0 * h2f(h0 & 0xffffu); ay0 += n0 * h2f(h0 >> 16);
    ax1 += n1 * h2f(h1 & 0xffffu); ay1 += n1 * h2f(h1 >> 16);
    ax2 += n2 * h2f(h2 & 0xffffu); ay2 += n2 * h2f(h2 >> 16);
    ax3 += n3 * h2f(h3 & 0xffffu); ay3 += n3 * h2f(h3 >> 16);
  }
  for (; p < p1; ++p) {
    int2 e0 = edges[p];
    float n0 = __int_as_float(e0.y);
    unsigned int h0 = *(const unsigned int*)(H1h + (size_t)e0.x * FH + lane * 2);
    ax0 += n0 * h2f(h0 & 0xffffu); ay0 += n0 * h2f(h0 >> 16);
  }
  float di = dinv[wid], sn = di * di;
  unsigned int hs = *(const unsigned int*)(H1h + (size_t)wid * FH + lane * 2);
  float ax = (ax0 + ax1) + (ax2 + ax3) + sn * h2f(hs & 0xffffu);
  float ay = (ay0 + ay1) + (ay2 + ay3) + sn * h2f(hs >> 16);
  float2 bv = ((const float2*)b1)[lane];
  float ox = fmaxf(ax + bv.x, 0.f);
  float oy = fmaxf(ay + bv.y, 0.f);
  ((unsigned int*)(A1h + (size_t)wid * FH))[lane] = f2h(ox) | (f2h(oy) << 16);
}

// ---------------- aggregation layer 2: out = A @ h2 + b2, 64 fp16 feats
__global__ __launch_bounds__(256) void agg2_kernel(
    const unsigned short* __restrict__ H2h, const int2* __restrict__ edges,
    const int* __restrict__ rowptr, const float* __restrict__ dinv,
    const float* __restrict__ b2, float* __restrict__ OUT, int N) {
  int wid = (blockIdx.x * 256 + threadIdx.x) >> 6;
  int lane = threadIdx.x & 63;
  if (wid >= N) return;
  int p0 = rowptr[wid], p1 = rowptr[wid + 1];
  float a0 = 0.f, a1v = 0.f, a2 = 0.f, a3 = 0.f;
  const unsigned long long* ep = (const unsigned long long*)edges;
  int p = p0;
  for (; p + 4 <= p1; p += 4) {
    unsigned long long e0 = __builtin_nontemporal_load(ep + p);
    unsigned long long e1 = __builtin_nontemporal_load(ep + p + 1);
    unsigned long long e2 = __builtin_nontemporal_load(ep + p + 2);
    unsigned long long e3 = __builtin_nontemporal_load(ep + p + 3);
    float v0 = h2f(H2h[(size_t)(unsigned int)(e0 & 0xffffffffu) * FO + lane]);
    float v1 = h2f(H2h[(size_t)(unsigned int)(e1 & 0xffffffffu) * FO + lane]);
    float v2 = h2f(H2h[(size_t)(unsigned int)(e2 & 0xffffffffu) * FO + lane]);
    float v3 = h2f(H2h[(size_t)(unsigned int)(e3 & 0xffffffffu) * FO + lane]);
    a0  += __uint_as_float((unsigned int)(e0 >> 32)) * v0;
    a1v += __uint_as_float((unsigned int)(e1 >> 32)) * v1;
    a2  += __uint_as_float((unsigned int)(e2 >> 32)) * v2;
    a3  += __uint_as_float((unsigned int)(e3 >> 32)) * v3;
  }
  for (; p < p1; ++p) {
    int2 e0 = edges[p];
    a0 += __int_as_float(e0.y) * h2f(H2h[(size_t)e0.x * FO + lane]);
  }
  float di = dinv[wid];
  float r = (a0 + a1v) + (a2 + a3) + di * di * h2f(H2h[(size_t)wid * FO + lane]);
  r += b2[lane];
  OUT[(size_t)wid * FO + lane] = r;
}

extern "C" void kernel_launch(void* const* d_in, const int* in_sizes, int n_in,
                              void* d_out, int out_size, void* d_ws, size_t ws_size,
                              hipStream_t stream) {
  const float* x  = (const float*)d_in[0];
  const int*   ei = (const int*)d_in[1];
  const float* ew = (const float*)d_in[2];
  const float* W1 = (const float*)d_in[3];
  const float* b1 = (const float*)d_in[4];
  const float* W2 = (const float*)d_in[5];
  const float* b2 = (const float*)d_in[6];
  float* out = (float*)d_out;

  const int N = in_sizes[0] / FIN;        // 100000
  const int E = in_sizes[2];              // 3200000
  const int* src = ei;
  const int* dst = ei + E;
  const int nb = (N + 1023) / 1024;       // scan blocks
  const int NBG = (N + 63) / 64;          // gemm1 blocks
  const int NBH = (E + 255) / 256;        // hist blocks
  // stripe-interleaved grid: bid%9==8 -> gemm g=bid/9; else hist (bid/9)*8+bid%9
  int bidH = ((NBH - 1) / RATIO) * (RATIO + 1) + ((NBH - 1) % RATIO);
  int bidG = (NBG - 1) * (RATIO + 1) + RATIO;
  int GRID = (bidH > bidG ? bidH : bidG) + 1;

  // workspace layout (16B-aligned slices), ~80MB total
  char* ws = (char*)d_ws;
  size_t off = 0;
  unsigned short* h1h = (unsigned short*)(ws + off); off += (size_t)N * FH * 2;  // fp16 h1
  unsigned short* h2h = (unsigned short*)(ws + off); off += (size_t)N * FO * 2;  // fp16 h2
  unsigned short* a1h = (unsigned short*)(ws + off); off += (size_t)N * FH * 2;  // fp16 a1
  int2*  edges  = (int2*) (ws + off); off += (size_t)E * 8;
  int*   pos    = (int*)  (ws + off); off += (size_t)E * 4;
  unsigned long long* cnt64 = (unsigned long long*)(ws + off); off += (size_t)N * 8;
  int*   rowptr = (int*)  (ws + off); off += (((size_t)(N + 1) * 4) + 15) & ~(size_t)15;
  float* dinv   = (float*)(ws + off); off += (size_t)N * 4;
  int*   bsum   = (int*)  (ws + off); off += 1024;

  hipMemsetAsync(cnt64, 0, (size_t)N * 8, stream);
  hist_gemm1_kernel<<<GRID, 256, 0, stream>>>(dst, ew, cnt64, pos, E,
                                              x, W1, h1h, N, NBG);
  scan1_kernel<<<nb, 256, 0, stream>>>(cnt64, rowptr, bsum, dinv, N);
  scan2_kernel<<<1, 256, 0, stream>>>(bsum, rowptr + N, nb, E);
  scan3_kernel<<<(N + 255) / 256, 256, 0, stream>>>(rowptr, bsum, N);
  scatter_kernel<<<(E + 255) / 256, 256, 0, stream>>>(src, dst, ew, rowptr, pos,
                                                      dinv, edges, E);
  agg1_kernel<<<(N * 64 + 255) / 256, 256, 0, stream>>>(h1h, edges, rowptr,
                                                        dinv, b1, a1h, N);
  gemm2_kernel<<<(N + 63) / 64, 256, 0, stream>>>(a1h, W2, h2h, N);
  agg2_kernel<<<(N * 64 + 255) / 256, 256, 0, stream>>>(h2h, edges, rowptr,
                                                        dinv, b2, out, N);
}

// Round 8
// 492.131 us; speedup vs baseline: 1.2141x; 1.2141x over previous
//
#include <hip/hip_runtime.h>
#include <hip/hip_bf16.h>

// GCN 2-layer encoder: N=100000 nodes, E=3.2M edges, Fin=256, Fh=128, Fo=64.
//   h1 = x@W1 ; a1 = relu(A@h1 + b1) ; h2 = a1@W2 ; out = A@h2 + b2
// A includes self-loops (w=1), symmetric rsqrt-degree normalization.
//
// R8: (a) REVERTED nontemporal edge loads (R7 regression: uniform broadcast
// stream wants the cache path). (b) agg1 half-wave gather: 32 lanes x 8B
// per row, 2 edges/wave x4 unroll = 8 rows in flight, xor(32) reduce.
// (c) agg2 quarter-wave: 16 lanes x 8B, 4 edges/wave x2 unroll, xor(16|32)
// reduce. Stripe-fused hist+gemm1 kept (R7: -17us). fp16 h1/a1/h2 kept.
// CSR via packed-u64 atomic (count<<42 | fixed-point wdeg; old>>42 = pos).

#define FIN 256
#define FH  128
#define FO  64

#define CNT_SHIFT 42
#define WSCALE 1073741824.0f          // 2^30
#define WINV   (1.0f / 1073741824.0f)
#define LOWMASK ((1ULL << CNT_SHIFT) - 1ULL)
#define RATIO 8                        // hist blocks per gemm block

__device__ __forceinline__ float h2f(unsigned int u16) {
  union { unsigned short s; _Float16 h; } c; c.s = (unsigned short)u16;
  return (float)c.h;
}
__device__ __forceinline__ unsigned int f2h(float f) {
  union { _Float16 h; unsigned short s; } c; c.h = (_Float16)f;  // RNE cvt
  return (unsigned int)c.s;
}

// ---------------- fused: stripe-interleaved hist (8/9) + gemm1 (1/9)
__global__ __launch_bounds__(256) void hist_gemm1_kernel(
    const int* __restrict__ dst, const float* __restrict__ w,
    unsigned long long* __restrict__ cnt64, int* __restrict__ pos, int E,
    const float* __restrict__ X, const float* __restrict__ W,
    unsigned short* __restrict__ H1h, int N, int NBG) {
  __shared__ __align__(16) float xs[64][17];
  __shared__ __align__(16) float wsm[16 * FH];
  int bid = blockIdx.x;
  int tid = threadIdx.x;
  int g = bid / (RATIO + 1);
  int r = bid - g * (RATIO + 1);
  if (r != RATIO) {
    // ---- histogram role: one u64 atomic per edge; returns stable position
    int e = (g * RATIO + r) * 256 + tid;
    if (e < E) {
      int d = dst[e];
      unsigned long long v = (1ULL << CNT_SHIFT)
                           + (unsigned long long)(w[e] * WSCALE);
      unsigned long long old = atomicAdd(&cnt64[d], v);
      pos[e] = (int)(old >> CNT_SHIFT);
    }
    return;
  }
  if (g >= NBG) return;
  // ---- gemm1 role: H1h[64 rows, 128 cols] fp16 = X @ W1
  int row0 = g * 64;
  int tx = tid & 31;        // cols tx*4 .. +3
  int ty = tid >> 5;        // rows ty*8 .. +7
  float acc[8][4];
  #pragma unroll
  for (int i = 0; i < 8; ++i)
    #pragma unroll
    for (int j = 0; j < 4; ++j) acc[i][j] = 0.f;

  for (int k0 = 0; k0 < FIN; k0 += 16) {
    {
      int rr = tid >> 2, kq = (tid & 3) * 4;
      int gr = row0 + rr;
      float4 v = make_float4(0.f, 0.f, 0.f, 0.f);
      if (gr < N) v = *(const float4*)(X + (size_t)gr * FIN + k0 + kq);
      xs[rr][kq + 0] = v.x; xs[rr][kq + 1] = v.y;
      xs[rr][kq + 2] = v.z; xs[rr][kq + 3] = v.w;
    }
    {
      const float4* s4 = (const float4*)(W + (size_t)k0 * FH);
      float4* d4 = (float4*)wsm;
      d4[tid] = s4[tid];
      d4[tid + 256] = s4[tid + 256];
    }
    __syncthreads();
    #pragma unroll
    for (int kk = 0; kk < 16; ++kk) {
      float xv[8];
      #pragma unroll
      for (int i = 0; i < 8; ++i) xv[i] = xs[ty * 8 + i][kk];
      float4 wv = *(const float4*)(&wsm[kk * FH + tx * 4]);
      #pragma unroll
      for (int i = 0; i < 8; ++i) {
        acc[i][0] += xv[i] * wv.x; acc[i][1] += xv[i] * wv.y;
        acc[i][2] += xv[i] * wv.z; acc[i][3] += xv[i] * wv.w;
      }
    }
    __syncthreads();
  }
  #pragma unroll
  for (int i = 0; i < 8; ++i) {
    int gr = row0 + ty * 8 + i;
    if (gr < N) {
      uint2 pk;
      pk.x = f2h(acc[i][0]) | (f2h(acc[i][1]) << 16);
      pk.y = f2h(acc[i][2]) | (f2h(acc[i][3]) << 16);
      *(uint2*)(H1h + (size_t)gr * FH + tx * 4) = pk;
    }
  }
}

// ---------------- 3-phase exclusive scan of cnt64>>42 -> rowptr; also dinv
__global__ __launch_bounds__(256) void scan1_kernel(
    const unsigned long long* __restrict__ cnt64, int* __restrict__ rowptr,
    int* __restrict__ bsum, float* __restrict__ dinv, int N) {
  __shared__ int tot[256];
  int t = threadIdx.x;
  int base = blockIdx.x * 1024 + t * 4;
  int v0 = 0, v1 = 0, v2 = 0, v3 = 0;
  #pragma unroll
  for (int q = 0; q < 4; ++q) {
    int idx = base + q;
    if (idx < N) {
      unsigned long long c = cnt64[idx];
      int cv = (int)(c >> CNT_SHIFT);
      float deg = (float)(c & LOWMASK) * WINV;
      dinv[idx] = rsqrtf(1.0f + deg);
      if (q == 0) v0 = cv; else if (q == 1) v1 = cv;
      else if (q == 2) v2 = cv; else v3 = cv;
    }
  }
  int s = v0 + v1 + v2 + v3;
  tot[t] = s;
  __syncthreads();
  for (int off = 1; off < 256; off <<= 1) {
    int y = (t >= off) ? tot[t - off] : 0;
    __syncthreads();
    tot[t] += y;
    __syncthreads();
  }
  int p = tot[t] - s;  // exclusive within block
  if (t == 255) bsum[blockIdx.x] = tot[255];
  if (base + 0 < N) rowptr[base + 0] = p; p += v0;
  if (base + 1 < N) rowptr[base + 1] = p; p += v1;
  if (base + 2 < N) rowptr[base + 2] = p; p += v2;
  if (base + 3 < N) rowptr[base + 3] = p;
}

__global__ __launch_bounds__(256) void scan2_kernel(
    int* __restrict__ bsum, int* __restrict__ rowptrN, int nb, int E) {
  __shared__ int buf[256];
  int t = threadIdx.x;
  int v = (t < nb) ? bsum[t] : 0;
  buf[t] = v;
  __syncthreads();
  for (int off = 1; off < 256; off <<= 1) {
    int y = (t >= off) ? buf[t - off] : 0;
    __syncthreads();
    buf[t] += y;
    __syncthreads();
  }
  if (t < nb) bsum[t] = buf[t] - v;  // exclusive
  if (t == 0) rowptrN[0] = E;
}

__global__ __launch_bounds__(256) void scan3_kernel(
    int* __restrict__ rowptr, const int* __restrict__ bsum, int N) {
  int i = blockIdx.x * 256 + threadIdx.x;
  if (i < N) rowptr[i] += bsum[i >> 10];
}

// ---------------- scatter (atomic-free): edges[rowptr[d]+pos[e]] = {src, norm}
__global__ __launch_bounds__(256) void scatter_kernel(
    const int* __restrict__ src, const int* __restrict__ dst,
    const float* __restrict__ w, const int* __restrict__ rowptr,
    const int* __restrict__ pos, const float* __restrict__ dinv,
    int2* __restrict__ edges, int E) {
  int e = blockIdx.x * 256 + threadIdx.x;
  if (e < E) {
    int s = src[e], d = dst[e];
    float nm = dinv[s] * w[e] * dinv[d];
    edges[rowptr[d] + pos[e]] = make_int2(s, __float_as_int(nm));
  }
}

// ---------------- GEMM2: H2h[N,64](fp16) = A1h[N,128](fp16) @ W2[128,64]
__global__ __launch_bounds__(256) void gemm2_kernel(
    const unsigned short* __restrict__ A1h, const float* __restrict__ W2,
    unsigned short* __restrict__ H2h, int N) {
  __shared__ __align__(16) float xs[64][17];
  __shared__ __align__(16) float ws[16 * FO];
  int tid = threadIdx.x;
  int row0 = blockIdx.x * 64;
  int tx = tid & 15;        // cols tx*4..+3
  int ty = tid >> 4;        // rows ty*4..+3
  float acc[4][4];
  #pragma unroll
  for (int i = 0; i < 4; ++i)
    #pragma unroll
    for (int j = 0; j < 4; ++j) acc[i][j] = 0.f;

  for (int k0 = 0; k0 < FH; k0 += 16) {
    {
      int r = tid >> 2, kq = (tid & 3) * 4;
      int gr = row0 + r;
      uint2 v = make_uint2(0u, 0u);
      if (gr < N) v = *(const uint2*)(A1h + (size_t)gr * FH + k0 + kq);
      xs[r][kq + 0] = h2f(v.x & 0xffffu); xs[r][kq + 1] = h2f(v.x >> 16);
      xs[r][kq + 2] = h2f(v.y & 0xffffu); xs[r][kq + 3] = h2f(v.y >> 16);
    }
    {
      const float4* s4 = (const float4*)(W2 + (size_t)k0 * FO);
      float4* d4 = (float4*)ws;
      d4[tid] = s4[tid];
    }
    __syncthreads();
    #pragma unroll
    for (int kk = 0; kk < 16; ++kk) {
      float xv[4];
      #pragma unroll
      for (int i = 0; i < 4; ++i) xv[i] = xs[ty * 4 + i][kk];
      float4 wv = *(const float4*)(&ws[kk * FO + tx * 4]);
      #pragma unroll
      for (int i = 0; i < 4; ++i) {
        acc[i][0] += xv[i] * wv.x; acc[i][1] += xv[i] * wv.y;
        acc[i][2] += xv[i] * wv.z; acc[i][3] += xv[i] * wv.w;
      }
    }
    __syncthreads();
  }
  #pragma unroll
  for (int i = 0; i < 4; ++i) {
    int gr = row0 + ty * 4 + i;
    if (gr < N) {
      uint2 pk;
      pk.x = f2h(acc[i][0]) | (f2h(acc[i][1]) << 16);
      pk.y = f2h(acc[i][2]) | (f2h(acc[i][3]) << 16);
      *(uint2*)(H2h + (size_t)gr * FO + tx * 4) = pk;
    }
  }
}

// ---------------- agg1: a1h = relu(A @ h1 + b1), 128 fp16 feats
// half-wave per row: 32 lanes x 8B; 2 edges/wave, x4 unroll = 8 rows in flight
__global__ __launch_bounds__(256) void agg1_kernel(
    const unsigned short* __restrict__ H1h, const int2* __restrict__ edges,
    const int* __restrict__ rowptr, const float* __restrict__ dinv,
    const float* __restrict__ b1, unsigned short* __restrict__ A1h, int N) {
  int wid = (blockIdx.x * 256 + threadIdx.x) >> 6;
  int lane = threadIdx.x & 63;
  if (wid >= N) return;
  int p0 = rowptr[wid], p1 = rowptr[wid + 1];
  int half = lane >> 5, li = lane & 31;     // li covers feats li*4..+3
  const size_t rowoff = (size_t)li * 4;
  float acc[4][4];
  #pragma unroll
  for (int u = 0; u < 4; ++u)
    #pragma unroll
    for (int j = 0; j < 4; ++j) acc[u][j] = 0.f;

  int p = p0;
  for (; p + 8 <= p1; p += 8) {
    int2 e0 = edges[p     + half];
    int2 e1 = edges[p + 2 + half];
    int2 e2 = edges[p + 4 + half];
    int2 e3 = edges[p + 6 + half];
    uint2 h0 = *(const uint2*)(H1h + (size_t)e0.x * FH + rowoff);
    uint2 h1 = *(const uint2*)(H1h + (size_t)e1.x * FH + rowoff);
    uint2 h2 = *(const uint2*)(H1h + (size_t)e2.x * FH + rowoff);
    uint2 h3 = *(const uint2*)(H1h + (size_t)e3.x * FH + rowoff);
    float n0 = __int_as_float(e0.y), n1 = __int_as_float(e1.y);
    float n2 = __int_as_float(e2.y), n3 = __int_as_float(e3.y);
    acc[0][0] += n0 * h2f(h0.x & 0xffffu); acc[0][1] += n0 * h2f(h0.x >> 16);
    acc[0][2] += n0 * h2f(h0.y & 0xffffu); acc[0][3] += n0 * h2f(h0.y >> 16);
    acc[1][0] += n1 * h2f(h1.x & 0xffffu); acc[1][1] += n1 * h2f(h1.x >> 16);
    acc[1][2] += n1 * h2f(h1.y & 0xffffu); acc[1][3] += n1 * h2f(h1.y >> 16);
    acc[2][0] += n2 * h2f(h2.x & 0xffffu); acc[2][1] += n2 * h2f(h2.x >> 16);
    acc[2][2] += n2 * h2f(h2.y & 0xffffu); acc[2][3] += n2 * h2f(h2.y >> 16);
    acc[3][0] += n3 * h2f(h3.x & 0xffffu); acc[3][1] += n3 * h2f(h3.x >> 16);
    acc[3][2] += n3 * h2f(h3.y & 0xffffu); acc[3][3] += n3 * h2f(h3.y >> 16);
  }
  for (; p + 2 <= p1; p += 2) {
    int2 e0 = edges[p + half];
    uint2 h0 = *(const uint2*)(H1h + (size_t)e0.x * FH + rowoff);
    float n0 = __int_as_float(e0.y);
    acc[0][0] += n0 * h2f(h0.x & 0xffffu); acc[0][1] += n0 * h2f(h0.x >> 16);
    acc[0][2] += n0 * h2f(h0.y & 0xffffu); acc[0][3] += n0 * h2f(h0.y >> 16);
  }
  if (p < p1) {  // one leftover edge: half 1 contributes 0
    int2 e0 = edges[p];
    float n0 = (half == 0) ? __int_as_float(e0.y) : 0.f;
    uint2 h0 = *(const uint2*)(H1h + (size_t)e0.x * FH + rowoff);
    acc[0][0] += n0 * h2f(h0.x & 0xffffu); acc[0][1] += n0 * h2f(h0.x >> 16);
    acc[0][2] += n0 * h2f(h0.y & 0xffffu); acc[0][3] += n0 * h2f(h0.y >> 16);
  }
  float s0 = (acc[0][0] + acc[1][0]) + (acc[2][0] + acc[3][0]);
  float s1 = (acc[0][1] + acc[1][1]) + (acc[2][1] + acc[3][1]);
  float s2 = (acc[0][2] + acc[1][2]) + (acc[2][2] + acc[3][2]);
  float s3 = (acc[0][3] + acc[1][3]) + (acc[2][3] + acc[3][3]);
  s0 += __shfl_xor(s0, 32);
  s1 += __shfl_xor(s1, 32);
  s2 += __shfl_xor(s2, 32);
  s3 += __shfl_xor(s3, 32);
  if (half == 0) {
    float di = dinv[wid], sn = di * di;
    uint2 hs = *(const uint2*)(H1h + (size_t)wid * FH + rowoff);
    s0 += sn * h2f(hs.x & 0xffffu); s1 += sn * h2f(hs.x >> 16);
    s2 += sn * h2f(hs.y & 0xffffu); s3 += sn * h2f(hs.y >> 16);
    float4 bv = *(const float4*)(b1 + li * 4);
    s0 = fmaxf(s0 + bv.x, 0.f); s1 = fmaxf(s1 + bv.y, 0.f);
    s2 = fmaxf(s2 + bv.z, 0.f); s3 = fmaxf(s3 + bv.w, 0.f);
    uint2 pk;
    pk.x = f2h(s0) | (f2h(s1) << 16);
    pk.y = f2h(s2) | (f2h(s3) << 16);
    *(uint2*)(A1h + (size_t)wid * FH + li * 4) = pk;
  }
}

// ---------------- agg2: out = A @ h2 + b2, 64 fp16 feats
// quarter-wave per row: 16 lanes x 8B; 4 edges/wave, x2 unroll = 8 in flight
__global__ __launch_bounds__(256) void agg2_kernel(
    const unsigned short* __restrict__ H2h, const int2* __restrict__ edges,
    const int* __restrict__ rowptr, const float* __restrict__ dinv,
    const float* __restrict__ b2, float* __restrict__ OUT, int N) {
  int wid = (blockIdx.x * 256 + threadIdx.x) >> 6;
  int lane = threadIdx.x & 63;
  if (wid >= N) return;
  int p0 = rowptr[wid], p1 = rowptr[wid + 1];
  int grp = lane >> 4, li = lane & 15;      // li covers feats li*4..+3
  const size_t rowoff = (size_t)li * 4;
  float acc[2][4];
  #pragma unroll
  for (int u = 0; u < 2; ++u)
    #pragma unroll
    for (int j = 0; j < 4; ++j) acc[u][j] = 0.f;

  int p = p0;
  for (; p + 8 <= p1; p += 8) {
    int2 e0 = edges[p + grp];
    int2 e1 = edges[p + 4 + grp];
    uint2 h0 = *(const uint2*)(H2h + (size_t)e0.x * FO + rowoff);
    uint2 h1 = *(const uint2*)(H2h + (size_t)e1.x * FO + rowoff);
    float n0 = __int_as_float(e0.y), n1 = __int_as_float(e1.y);
    acc[0][0] += n0 * h2f(h0.x & 0xffffu); acc[0][1] += n0 * h2f(h0.x >> 16);
    acc[0][2] += n0 * h2f(h0.y & 0xffffu); acc[0][3] += n0 * h2f(h0.y >> 16);
    acc[1][0] += n1 * h2f(h1.x & 0xffffu); acc[1][1] += n1 * h2f(h1.x >> 16);
    acc[1][2] += n1 * h2f(h1.y & 0xffffu); acc[1][3] += n1 * h2f(h1.y >> 16);
  }
  for (; p + 4 <= p1; p += 4) {
    int2 e0 = edges[p + grp];
    uint2 h0 = *(const uint2*)(H2h + (size_t)e0.x * FO + rowoff);
    float n0 = __int_as_float(e0.y);
    acc[0][0] += n0 * h2f(h0.x & 0xffffu); acc[0][1] += n0 * h2f(h0.x >> 16);
    acc[0][2] += n0 * h2f(h0.y & 0xffffu); acc[0][3] += n0 * h2f(h0.y >> 16);
  }
  if (p < p1) {  // 1..3 leftover edges
    int q = p + grp;
    int qi = (q < p1) ? q : p;
    int2 e0 = edges[qi];
    float n0 = (q < p1) ? __int_as_float(e0.y) : 0.f;
    uint2 h0 = *(const uint2*)(H2h + (size_t)e0.x * FO + rowoff);
    acc[0][0] += n0 * h2f(h0.x & 0xffffu); acc[0][1] += n0 * h2f(h0.x >> 16);
    acc[0][2] += n0 * h2f(h0.y & 0xffffu); acc[0][3] += n0 * h2f(h0.y >> 16);
  }
  float s0 = acc[0][0] + acc[1][0];
  float s1 = acc[0][1] + acc[1][1];
  float s2 = acc[0][2] + acc[1][2];
  float s3 = acc[0][3] + acc[1][3];
  s0 += __shfl_xor(s0, 16); s0 += __shfl_xor(s0, 32);
  s1 += __shfl_xor(s1, 16); s1 += __shfl_xor(s1, 32);
  s2 += __shfl_xor(s2, 16); s2 += __shfl_xor(s2, 32);
  s3 += __shfl_xor(s3, 16); s3 += __shfl_xor(s3, 32);
  if (lane < 16) {
    float di = dinv[wid], sn = di * di;
    uint2 hs = *(const uint2*)(H2h + (size_t)wid * FO + rowoff);
    s0 += sn * h2f(hs.x & 0xffffu); s1 += sn * h2f(hs.x >> 16);
    s2 += sn * h2f(hs.y & 0xffffu); s3 += sn * h2f(hs.y >> 16);
    float4 bv = *(const float4*)(b2 + li * 4);
    float4 o = make_float4(s0 + bv.x, s1 + bv.y, s2 + bv.z, s3 + bv.w);
    *(float4*)(OUT + (size_t)wid * FO + li * 4) = o;
  }
}

extern "C" void kernel_launch(void* const* d_in, const int* in_sizes, int n_in,
                              void* d_out, int out_size, void* d_ws, size_t ws_size,
                              hipStream_t stream) {
  const float* x  = (const float*)d_in[0];
  const int*   ei = (const int*)d_in[1];
  const float* ew = (const float*)d_in[2];
  const float* W1 = (const float*)d_in[3];
  const float* b1 = (const float*)d_in[4];
  const float* W2 = (const float*)d_in[5];
  const float* b2 = (const float*)d_in[6];
  float* out = (float*)d_out;

  const int N = in_sizes[0] / FIN;        // 100000
  const int E = in_sizes[2];              // 3200000
  const int* src = ei;
  const int* dst = ei + E;
  const int nb = (N + 1023) / 1024;       // scan blocks
  const int NBG = (N + 63) / 64;          // gemm1 blocks
  const int NBH = (E + 255) / 256;        // hist blocks
  // stripe-interleaved grid: bid%9==8 -> gemm g=bid/9; else hist (bid/9)*8+bid%9
  int bidH = ((NBH - 1) / RATIO) * (RATIO + 1) + ((NBH - 1) % RATIO);
  int bidG = (NBG - 1) * (RATIO + 1) + RATIO;
  int GRID = (bidH > bidG ? bidH : bidG) + 1;

  // workspace layout (16B-aligned slices), ~80MB total
  char* ws = (char*)d_ws;
  size_t off = 0;
  unsigned short* h1h = (unsigned short*)(ws + off); off += (size_t)N * FH * 2;  // fp16 h1
  unsigned short* h2h = (unsigned short*)(ws + off); off += (size_t)N * FO * 2;  // fp16 h2
  unsigned short* a1h = (unsigned short*)(ws + off); off += (size_t)N * FH * 2;  // fp16 a1
  int2*  edges  = (int2*) (ws + off); off += (size_t)E * 8;
  int*   pos    = (int*)  (ws + off); off += (size_t)E * 4;
  unsigned long long* cnt64 = (unsigned long long*)(ws + off); off += (size_t)N * 8;
  int*   rowptr = (int*)  (ws + off); off += (((size_t)(N + 1) * 4) + 15) & ~(size_t)15;
  float* dinv   = (float*)(ws + off); off += (size_t)N * 4;
  int*   bsum   = (int*)  (ws + off); off += 1024;

  hipMemsetAsync(cnt64, 0, (size_t)N * 8, stream);
  hist_gemm1_kernel<<<GRID, 256, 0, stream>>>(dst, ew, cnt64, pos, E,
                                              x, W1, h1h, N, NBG);
  scan1_kernel<<<nb, 256, 0, stream>>>(cnt64, rowptr, bsum, dinv, N);
  scan2_kernel<<<1, 256, 0, stream>>>(bsum, rowptr + N, nb, E);
  scan3_kernel<<<(N + 255) / 256, 256, 0, stream>>>(rowptr, bsum, N);
  scatter_kernel<<<(E + 255) / 256, 256, 0, stream>>>(src, dst, ew, rowptr, pos,
                                                      dinv, edges, E);
  agg1_kernel<<<(N * 64 + 255) / 256, 256, 0, stream>>>(h1h, edges, rowptr,
                                                        dinv, b1, a1h, N);
  gemm2_kernel<<<(N + 63) / 64, 256, 0, stream>>>(a1h, W2, h2h, N);
  agg2_kernel<<<(N * 64 + 255) / 256, 256, 0, stream>>>(h2h, edges, rowptr,
                                                        dinv, b2, out, N);
}